// Round 13
// baseline (692.738 us; speedup 1.0000x reference)
//
#include <hip/hip_runtime.h>
#include <hip/hip_bf16.h>

typedef __attribute__((ext_vector_type(8))) short short8;
typedef __attribute__((ext_vector_type(4))) float f32x4;
typedef unsigned long long u64;

// z: [64, 256, 32, 32] f32 ; codebook: [512, 256] f32
// d_out f32: [z_q_st (16777216) | indices (65536) | loss (1)]
#define C_DIM   256
#define K_CODES 512
#define N_POS   65536
#define OUT0_ELEMS 16777216
#define OUT1_ELEMS 65536
#define EPS 0.25f   // hi-only screen: worst-case 2E ~= 0.12, 2x margin
#define LCAP 2048   // candidate list cap per 32-pos block

// ---------------------------------------------------------------------------
// codebook -> bf16 rows (hi only)
// ---------------------------------------------------------------------------
__global__ __launch_bounds__(256) void vq_convcb_kernel(const float* __restrict__ cb,
    __hip_bfloat16* __restrict__ Ch)
{
    const int i = blockIdx.x * 256 + threadIdx.x;
    Ch[i] = __float2bfloat16(cb[i]);
}

// ---------------------------------------------------------------------------
// cc[k] = sum_c cb[k][c]^2, numpy pairwise order (proven)
// ---------------------------------------------------------------------------
__global__ __launch_bounds__(256) void vq_cc_kernel(const float* __restrict__ cb,
                                                    float* __restrict__ cc)
{
    const int k = blockIdx.x * 256 + threadIdx.x;
    const float* row = cb + (size_t)k * C_DIM;
    float s1[8], s2[8];
    #pragma unroll
    for (int j = 0; j < 8; ++j) { s1[j] = 0.f; s2[j] = 0.f; }
    for (int c8 = 0; c8 < 16; ++c8)
        #pragma unroll
        for (int j = 0; j < 8; ++j) {
            float v = row[c8 * 8 + j];
            s1[j] = __fadd_rn(s1[j], __fmul_rn(v, v));
        }
    for (int c8 = 16; c8 < 32; ++c8)
        #pragma unroll
        for (int j = 0; j < 8; ++j) {
            float v = row[c8 * 8 + j];
            s2[j] = __fadd_rn(s2[j], __fmul_rn(v, v));
        }
    float b1 = __fadd_rn(__fadd_rn(__fadd_rn(s1[0], s1[1]), __fadd_rn(s1[2], s1[3])),
                         __fadd_rn(__fadd_rn(s1[4], s1[5]), __fadd_rn(s1[6], s1[7])));
    float b2 = __fadd_rn(__fadd_rn(__fadd_rn(s2[0], s2[1]), __fadd_rn(s2[2], s2[3])),
                         __fadd_rn(__fadd_rn(s2[4], s2[5]), __fadd_rn(s2[6], s2[7])));
    cc[k] = __fadd_rn(b1, b2);
}

// ---------------------------------------------------------------------------
// zz[pos] = sum_c z[pos][c]^2, np-pairwise (proven)
// ---------------------------------------------------------------------------
__global__ __launch_bounds__(256) void vq_zz_kernel(const float* __restrict__ z,
                                                    float* __restrict__ zz)
{
    const int pos = blockIdx.x * 256 + threadIdx.x;
    const float* zp = z + ((size_t)(pos >> 10) << 18) + (pos & 1023);
    float s1[8], s2[8];
    #pragma unroll
    for (int j = 0; j < 8; ++j) { s1[j] = 0.f; s2[j] = 0.f; }
    for (int c8 = 0; c8 < 16; ++c8)
        #pragma unroll
        for (int j = 0; j < 8; ++j) {
            float v = zp[(size_t)(c8 * 8 + j) << 10];
            s1[j] = __fadd_rn(s1[j], __fmul_rn(v, v));
        }
    for (int c8 = 16; c8 < 32; ++c8)
        #pragma unroll
        for (int j = 0; j < 8; ++j) {
            float v = zp[(size_t)(c8 * 8 + j) << 10];
            s2[j] = __fadd_rn(s2[j], __fmul_rn(v, v));
        }
    float b1 = __fadd_rn(__fadd_rn(__fadd_rn(s1[0], s1[1]), __fadd_rn(s1[2], s1[3])),
                         __fadd_rn(__fadd_rn(s1[4], s1[5]), __fadd_rn(s1[6], s1[7])));
    float b2 = __fadd_rn(__fadd_rn(__fadd_rn(s2[0], s2[1]), __fadd_rn(s2[2], s2[3])),
                         __fadd_rn(__fadd_rn(s2[4], s2[5]), __fadd_rn(s2[6], s2[7])));
    zz[pos] = __fadd_rn(b1, b2);
}

// ---------------------------------------------------------------------------
// z -> Zh bf16 in [pos][c] layout (unchanged, passed)
// ---------------------------------------------------------------------------
__global__ __launch_bounds__(256) void vq_splitz_kernel(const float* __restrict__ z,
    __hip_bfloat16* __restrict__ Zh)
{
    const int tid = threadIdx.x;
    const int p   = blockIdx.x * 32 + (tid >> 3);
    const int c8  = tid & 7;
    const float* zb = z + ((size_t)(p >> 10) << 18) + (p & 1023);
    __hip_bfloat16* out = Zh + (size_t)p * C_DIM;
    #pragma unroll
    for (int q = 0; q < 4; ++q) {
        const int c0 = q * 64 + c8 * 8;
        short8 pk;
        #pragma unroll
        for (int j = 0; j < 8; ++j) {
            float v = zb[(size_t)(c0 + j) << 10];
            __hip_bfloat16 h = __float2bfloat16(v);
            pk[j] = *reinterpret_cast<short*>(&h);
        }
        *reinterpret_cast<short8*>(out + c0) = pk;
    }
}

// ---------------------------------------------------------------------------
// MFMA screen (hi-only): bd[pos][sg] = min over 16 codes of cc - 2*(Zh.Ch)
// Layout transposed vs R12: bd[pos*32 + sg] for coalesced per-pos reads.
// ---------------------------------------------------------------------------
__global__ __launch_bounds__(256) void vq_mfma_kernel(
    const __hip_bfloat16* __restrict__ Zh, const __hip_bfloat16* __restrict__ Ch,
    const float* __restrict__ ccv, float* __restrict__ bd)
{
    const int blk  = blockIdx.x;
    const int cg   = blk & 1;
    const int pt   = blk >> 1;
    const int tid  = threadIdx.x;
    const int lane = tid & 63;
    const int w    = tid >> 6;
    const int r16  = lane & 15;
    const int kg   = lane >> 4;
    const int code0 = cg * 256 + w * 64;

    f32x4 acc[4][4];
    #pragma unroll
    for (int mf = 0; mf < 4; ++mf)
        #pragma unroll
        for (int nf = 0; nf < 4; ++nf) acc[mf][nf] = (f32x4){0.f, 0.f, 0.f, 0.f};

    for (int kk = 0; kk < 8; ++kk) {
        const int cc0 = kk * 32 + kg * 8;
        short8 a[4];
        #pragma unroll
        for (int mf = 0; mf < 4; ++mf) {
            const int pos = (pt << 6) + (mf << 4) + r16;
            a[mf] = *reinterpret_cast<const short8*>(Zh + (size_t)pos * C_DIM + cc0);
        }
        #pragma unroll
        for (int nf = 0; nf < 4; ++nf) {
            const int code = code0 + nf * 16 + r16;
            short8 bh = *reinterpret_cast<const short8*>(Ch + (size_t)code * C_DIM + cc0);
            #pragma unroll
            for (int mf = 0; mf < 4; ++mf)
                acc[mf][nf] = __builtin_amdgcn_mfma_f32_16x16x32_bf16(a[mf], bh, acc[mf][nf], 0, 0, 0);
        }
    }

    #pragma unroll
    for (int nf = 0; nf < 4; ++nf) {
        const float cck = ccv[code0 + nf * 16 + r16];
        const int sg = (code0 >> 4) + nf;
        #pragma unroll
        for (int mf = 0; mf < 4; ++mf) {
            #pragma unroll
            for (int r = 0; r < 4; ++r) {
                float s = __builtin_fmaf(-2.0f, acc[mf][nf][r], cck);
                s = fminf(s, __shfl_xor(s, 1));
                s = fminf(s, __shfl_xor(s, 2));
                s = fminf(s, __shfl_xor(s, 4));
                s = fminf(s, __shfl_xor(s, 8));
                if (r16 == 0) {
                    const int pos = (pt << 6) + (mf << 4) + (kg << 2) + r;
                    bd[((size_t)pos << 5) + sg] = s;     // transposed layout
                }
            }
        }
    }
}

// ---------------------------------------------------------------------------
// Exact re-check v3: block = 32 positions. z staged in LDS (coalesced).
// Screen scan: thread p<32 reads bd[pos][0..32) as 8 consecutive float4
// (2 cache lines, coalesced across threads), computes min+mask in registers,
// pushes candidate chunks. Drain: dual-entry interleave (2 independent exact
// chains/thread) to cover FMA-chain latency. Chain numerics identical to
// R11/R12 (passed): ascending-c single-acc FMA, d = fl(fl(zz-2*dot)+cc);
// atomicMin on packed (d_bits<<32|code). Overflow processed inline.
// ---------------------------------------------------------------------------
__global__ __launch_bounds__(256) void vq_exact_kernel(
    const float* __restrict__ z, const float* __restrict__ cb,
    const float* __restrict__ ccv, const float* __restrict__ zzbuf,
    const float* __restrict__ bd, u64* __restrict__ key)
{
    const int blk  = blockIdx.x;        // 0..2047, 32 pos each
    const int pos0 = blk << 5;
    const int tid  = threadIdx.x;

    __shared__ float zl[C_DIM * 32];    // 32 KB, zl[c*32 + p]
    __shared__ unsigned short list[LCAP];
    __shared__ int cnt;

    if (tid == 0) cnt = 0;
    __syncthreads();

    // ---- stage z: fully coalesced (32 consecutive pos per c)
    const float* zg = z + ((size_t)(pos0 >> 10) << 18) + (pos0 & 1023);
    for (int i = 0; i < 32; ++i) {
        const int idx = i * 256 + tid;
        const int c = idx >> 5;
        const int p = idx & 31;
        zl[c * 32 + p] = zg[((size_t)c << 10) + p];
    }

    // ---- screen scan + push (threads 0..31; coalesced vector bd reads)
    if (tid < 32) {
        const int p = tid;
        const float4* bp = reinterpret_cast<const float4*>(bd + ((size_t)(pos0 + p) << 5));
        float4 v[8];
        #pragma unroll
        for (int i = 0; i < 8; ++i) v[i] = bp[i];
        float m = 3.4e38f;
        #pragma unroll
        for (int i = 0; i < 8; ++i)
            m = fminf(m, fminf(fminf(v[i].x, v[i].y), fminf(v[i].z, v[i].w)));
        const float thr = m + EPS;
        const float zzv = zzbuf[pos0 + p];
        #pragma unroll
        for (int i = 0; i < 8; ++i) {
            const float bv[4] = {v[i].x, v[i].y, v[i].z, v[i].w};
            #pragma unroll
            for (int jj = 0; jj < 4; ++jj) {
                if (bv[jj] <= thr) {
                    const int g = i * 4 + jj;
                    int base = atomicAdd(&cnt, 16);
                    if (base + 16 <= LCAP) {
                        #pragma unroll
                        for (int j = 0; j < 16; ++j)
                            list[base + j] = (unsigned short)((p << 9) | (g * 16 + j));
                    } else {
                        // overflow: process inline (rare)
                        float bestd = 3.4e38f; int bestc = 0;
                        for (int j = 0; j < 16; ++j) {
                            const int code = g * 16 + j;
                            const float4* crow4 = reinterpret_cast<const float4*>(cb + ((size_t)code << 8));
                            float a0 = 0.f;
                            for (int c4 = 0; c4 < 64; ++c4) {
                                float4 cv = crow4[c4];
                                a0 = __builtin_fmaf(zl[(c4 * 4 + 0) * 32 + p], cv.x, a0);
                                a0 = __builtin_fmaf(zl[(c4 * 4 + 1) * 32 + p], cv.y, a0);
                                a0 = __builtin_fmaf(zl[(c4 * 4 + 2) * 32 + p], cv.z, a0);
                                a0 = __builtin_fmaf(zl[(c4 * 4 + 3) * 32 + p], cv.w, a0);
                            }
                            float d = __fadd_rn(__fsub_rn(zzv, __fmul_rn(2.0f, a0)), ccv[code]);
                            if (d < bestd) { bestd = d; bestc = code; }
                        }
                        u64 pk = ((u64)__float_as_uint(bestd) << 32) | (unsigned)bestc;
                        atomicMin(&key[pos0 + p], pk);
                    }
                }
            }
        }
    }
    __syncthreads();

    // ---- drain list: dual-entry interleave for chain-latency cover
    const int total = min(cnt, LCAP);
    for (int e = tid; e < total; e += 512) {
        const int e2 = e + 256;
        const bool has2 = e2 < total;
        const unsigned short ent1 = list[e];
        const unsigned short ent2 = list[has2 ? e2 : e];
        const int p1 = ent1 >> 9, code1 = ent1 & 511;
        const int p2 = ent2 >> 9, code2 = ent2 & 511;
        const float4* r1 = reinterpret_cast<const float4*>(cb + ((size_t)code1 << 8));
        const float4* r2 = reinterpret_cast<const float4*>(cb + ((size_t)code2 << 8));
        float a1 = 0.f, a2 = 0.f;
        for (int c4 = 0; c4 < 64; ++c4) {
            float4 cv1 = r1[c4];
            float4 cv2 = r2[c4];
            a1 = __builtin_fmaf(zl[(c4 * 4 + 0) * 32 + p1], cv1.x, a1);
            a2 = __builtin_fmaf(zl[(c4 * 4 + 0) * 32 + p2], cv2.x, a2);
            a1 = __builtin_fmaf(zl[(c4 * 4 + 1) * 32 + p1], cv1.y, a1);
            a2 = __builtin_fmaf(zl[(c4 * 4 + 1) * 32 + p2], cv2.y, a2);
            a1 = __builtin_fmaf(zl[(c4 * 4 + 2) * 32 + p1], cv1.z, a1);
            a2 = __builtin_fmaf(zl[(c4 * 4 + 2) * 32 + p2], cv2.z, a2);
            a1 = __builtin_fmaf(zl[(c4 * 4 + 3) * 32 + p1], cv1.w, a1);
            a2 = __builtin_fmaf(zl[(c4 * 4 + 3) * 32 + p2], cv2.w, a2);
        }
        float d1 = __fadd_rn(__fsub_rn(zzbuf[pos0 + p1], __fmul_rn(2.0f, a1)), ccv[code1]);
        u64 pk1 = ((u64)__float_as_uint(d1) << 32) | (unsigned)code1;
        atomicMin(&key[pos0 + p1], pk1);
        if (has2) {
            float d2 = __fadd_rn(__fsub_rn(zzbuf[pos0 + p2], __fmul_rn(2.0f, a2)), ccv[code2]);
            u64 pk2 = ((u64)__float_as_uint(d2) << 32) | (unsigned)code2;
            atomicMin(&key[pos0 + p2], pk2);
        }
    }
}

// ---------------------------------------------------------------------------
// Final: decode key -> idx, out1; per-block d_min sums -> partials[256]
// ---------------------------------------------------------------------------
__global__ __launch_bounds__(256) void vq_final_kernel(
    const u64* __restrict__ key, int* __restrict__ idx,
    float* __restrict__ out1, float* __restrict__ partials)
{
    const int t = threadIdx.x;
    const int pos = blockIdx.x * 256 + t;
    u64 k = key[pos];
    const int code = (int)(unsigned)(k & 0xffffffffull);
    const float d  = __uint_as_float((unsigned)(k >> 32));
    idx[pos]  = code;
    out1[pos] = (float)code;

    __shared__ float s[256];
    s[t] = d;
    __syncthreads();
    for (int off = 128; off > 0; off >>= 1) {
        if (t < off) s[t] += s[t + off];
        __syncthreads();
    }
    if (t == 0) partials[blockIdx.x] = s[0];
}

// ---------------------------------------------------------------------------
// Gather: out0[b, c, hw] = cb[code][c]  (f32) — proven kernel
// ---------------------------------------------------------------------------
__global__ __launch_bounds__(256) void vq_gather_kernel(
    const float* __restrict__ cb, const int* __restrict__ idx,
    float* __restrict__ out0)
{
    const int blk = blockIdx.x;          // 1024
    const int b   = blk >> 4;
    const int hw0 = (blk & 15) << 6;
    const int lane = threadIdx.x & 63;
    const int w    = threadIdx.x >> 6;

    __shared__ int sidx[64];
    if (threadIdx.x < 64) sidx[threadIdx.x] = idx[(blk << 6) + threadIdx.x];
    __syncthreads();

    const int code = sidx[lane];
    const float4* crow4 = reinterpret_cast<const float4*>(cb + ((size_t)code << 8) + (w << 6));
    float* ob = out0 + ((size_t)b << 18) + ((size_t)(w * 64) << 10) + hw0 + lane;
    #pragma unroll 4
    for (int j4 = 0; j4 < 16; ++j4) {
        float4 v = crow4[j4];
        ob[(size_t)(j4 * 4 + 0) << 10] = v.x;
        ob[(size_t)(j4 * 4 + 1) << 10] = v.y;
        ob[(size_t)(j4 * 4 + 2) << 10] = v.z;
        ob[(size_t)(j4 * 4 + 3) << 10] = v.w;
    }
}

// ---------------------------------------------------------------------------
// Finalize: loss = 1.25 * sum(partials[0..255]) / 2^24
// ---------------------------------------------------------------------------
__global__ __launch_bounds__(256) void vq_finalize_kernel(
    const float* __restrict__ partials, float* __restrict__ out2)
{
    __shared__ float s[256];
    const int t = threadIdx.x;
    s[t] = partials[t];
    __syncthreads();
    for (int off = 128; off > 0; off >>= 1) {
        if (t < off) s[t] += s[t + off];
        __syncthreads();
    }
    if (t == 0)
        out2[0] = 1.25f * (s[0] * (1.0f / 16777216.0f));
}

// ---------------------------------------------------------------------------
extern "C" void kernel_launch(void* const* d_in, const int* in_sizes, int n_in,
                              void* d_out, int out_size, void* d_ws, size_t ws_size,
                              hipStream_t stream)
{
    const float* z  = (const float*)d_in[0];
    const float* cb = (const float*)d_in[1];

    float* out0 = (float*)d_out;
    float* out1 = out0 + OUT0_ELEMS;
    float* out2 = out1 + OUT1_ELEMS;

    // scratch carved from out0 (all dead before gather overwrites):
    __hip_bfloat16* Zh = (__hip_bfloat16*)out0;     // 16M bf16 = [0, 8388608) f32-slots
    float* bd  = out0 + 8388608;                    // [pos][32] = 2M f32
    u64*   key = (u64*)(out0 + 10485760);           // 65536 u64
    float* zzb = out0 + 10616832;                   // 65536 f32

    // ws (~528 KB):
    float* wsf      = (float*)d_ws;
    float* ccv      = wsf;                                   // 512 f32
    float* partials = wsf + 512;                             // 256 f32
    __hip_bfloat16* Ch = (__hip_bfloat16*)(wsf + 1024);      // 131072 bf16
    int* idx        = (int*)(wsf + 66560);                   // 65536 i32

    hipMemsetAsync(key, 0xFF, N_POS * sizeof(u64), stream);
    hipLaunchKernelGGL(vq_convcb_kernel,  dim3(512),  dim3(256), 0, stream, cb, Ch);
    hipLaunchKernelGGL(vq_cc_kernel,      dim3(2),    dim3(256), 0, stream, cb, ccv);
    hipLaunchKernelGGL(vq_splitz_kernel,  dim3(2048), dim3(256), 0, stream, z, Zh);
    hipLaunchKernelGGL(vq_zz_kernel,      dim3(256),  dim3(256), 0, stream, z, zzb);
    hipLaunchKernelGGL(vq_mfma_kernel,    dim3(2048), dim3(256), 0, stream,
                       Zh, Ch, ccv, bd);
    hipLaunchKernelGGL(vq_exact_kernel,   dim3(2048), dim3(256), 0, stream,
                       z, cb, ccv, zzb, bd, key);
    hipLaunchKernelGGL(vq_final_kernel,   dim3(256),  dim3(256), 0, stream,
                       key, idx, out1, partials);
    hipLaunchKernelGGL(vq_gather_kernel,  dim3(1024), dim3(256), 0, stream, cb, idx, out0);
    hipLaunchKernelGGL(vq_finalize_kernel, dim3(1),   dim3(256), 0, stream, partials, out2);
}

// Round 14
// 316.468 us; speedup vs baseline: 2.1890x; 2.1890x over previous
//
#include <hip/hip_runtime.h>
#include <hip/hip_bf16.h>

typedef __attribute__((ext_vector_type(8))) short short8;
typedef __attribute__((ext_vector_type(4))) float f32x4;

// z: [64, 256, 32, 32] f32 ; codebook: [512, 256] f32
// d_out f32: [z_q_st (16777216) | indices (65536) | loss (1)]
#define C_DIM   256
#define K_CODES 512
#define N_POS   65536
#define OUT0_ELEMS 16777216
#define OUT1_ELEMS 65536
#define W_AMB 2.0e-3f     // screen worst-case ordering error ~3e-4; 6x margin
#define LDSW 257          // padded LDS row stride (floats)

// ---------------------------------------------------------------------------
// codebook -> bf16 hi/lo rows
// ---------------------------------------------------------------------------
__global__ __launch_bounds__(256) void vq_convcb_kernel(const float* __restrict__ cb,
    __hip_bfloat16* __restrict__ Ch, __hip_bfloat16* __restrict__ Cl)
{
    const int i = blockIdx.x * 256 + threadIdx.x;
    float v = cb[i];
    __hip_bfloat16 h = __float2bfloat16(v);
    __hip_bfloat16 l = __float2bfloat16(v - __bfloat162float(h));
    Ch[i] = h; Cl[i] = l;
}

// ---------------------------------------------------------------------------
// cc[k] = sum_c cb[k][c]^2, numpy pairwise order (proven)
// ---------------------------------------------------------------------------
__global__ __launch_bounds__(256) void vq_cc_kernel(const float* __restrict__ cb,
                                                    float* __restrict__ cc)
{
    const int k = blockIdx.x * 256 + threadIdx.x;
    const float* row = cb + (size_t)k * C_DIM;
    float s1[8], s2[8];
    #pragma unroll
    for (int j = 0; j < 8; ++j) { s1[j] = 0.f; s2[j] = 0.f; }
    for (int c8 = 0; c8 < 16; ++c8)
        #pragma unroll
        for (int j = 0; j < 8; ++j) {
            float v = row[c8 * 8 + j];
            s1[j] = __fadd_rn(s1[j], __fmul_rn(v, v));
        }
    for (int c8 = 16; c8 < 32; ++c8)
        #pragma unroll
        for (int j = 0; j < 8; ++j) {
            float v = row[c8 * 8 + j];
            s2[j] = __fadd_rn(s2[j], __fmul_rn(v, v));
        }
    float b1 = __fadd_rn(__fadd_rn(__fadd_rn(s1[0], s1[1]), __fadd_rn(s1[2], s1[3])),
                         __fadd_rn(__fadd_rn(s1[4], s1[5]), __fadd_rn(s1[6], s1[7])));
    float b2 = __fadd_rn(__fadd_rn(__fadd_rn(s2[0], s2[1]), __fadd_rn(s2[2], s2[3])),
                         __fadd_rn(__fadd_rn(s2[4], s2[5]), __fadd_rn(s2[6], s2[7])));
    cc[k] = __fadd_rn(b1, b2);
}

// ---------------------------------------------------------------------------
// Screen: one block = 64 positions x ALL 512 codes, 3-term split MFMA.
// z staged fp32 in LDS (pad 257), bf16 hi/lo fragments built in-register.
// Tracks per-pos (best_d, best_c, second_d) of screen d = cc - 2*dot.
// Also computes zz[pos] (np-pairwise, from LDS) for the exact chains.
// Fragment/layout conventions identical to R11-R13 (verified passing).
// ---------------------------------------------------------------------------
__global__ __launch_bounds__(256) void vq_screen_kernel(
    const float* __restrict__ z, const __hip_bfloat16* __restrict__ Ch,
    const __hip_bfloat16* __restrict__ Cl, const float* __restrict__ ccv,
    float* __restrict__ zzv, float* __restrict__ bestd,
    int* __restrict__ bestc, float* __restrict__ secondd)
{
    const int pt   = blockIdx.x;          // 0..1023 (64-pos tile)
    const int b    = pt >> 4;
    const int hw0  = (pt & 15) << 6;
    const int tid  = threadIdx.x;
    const int lane = tid & 63;
    const int w    = tid >> 6;
    const int r16  = lane & 15;
    const int kg   = lane >> 4;

    __shared__ float zt[64 * LDSW];       // [p][c], ~64.25 KB
    __shared__ float wb[4][64];
    __shared__ float wsec[4][64];
    __shared__ int   wc[4][64];

    // ---- stage z tile (fp32, coalesced float4 reads)
    const float4* zg4 = reinterpret_cast<const float4*>(z + ((size_t)b << 18) + hw0);
    #pragma unroll
    for (int it = 0; it < 16; ++it) {
        const int f4 = it * 256 + tid;    // 0..4095
        const int c  = f4 >> 4;
        const int p4 = f4 & 15;
        float4 v = zg4[(c << 8) + p4];
        zt[(p4 * 4 + 0) * LDSW + c] = v.x;
        zt[(p4 * 4 + 1) * LDSW + c] = v.y;
        zt[(p4 * 4 + 2) * LDSW + c] = v.z;
        zt[(p4 * 4 + 3) * LDSW + c] = v.w;
    }
    __syncthreads();

    // ---- zz (np-pairwise, proven order), 16 lanes per wave -> 64 pos
    if (lane < 16) {
        const int pl = w * 16 + lane;
        const float* zr = &zt[pl * LDSW];
        float s1[8], s2[8];
        #pragma unroll
        for (int j = 0; j < 8; ++j) { s1[j] = 0.f; s2[j] = 0.f; }
        for (int c8 = 0; c8 < 16; ++c8)
            #pragma unroll
            for (int j = 0; j < 8; ++j) {
                float v = zr[c8 * 8 + j];
                s1[j] = __fadd_rn(s1[j], __fmul_rn(v, v));
            }
        for (int c8 = 16; c8 < 32; ++c8)
            #pragma unroll
            for (int j = 0; j < 8; ++j) {
                float v = zr[c8 * 8 + j];
                s2[j] = __fadd_rn(s2[j], __fmul_rn(v, v));
            }
        float b1 = __fadd_rn(__fadd_rn(__fadd_rn(s1[0], s1[1]), __fadd_rn(s1[2], s1[3])),
                             __fadd_rn(__fadd_rn(s1[4], s1[5]), __fadd_rn(s1[6], s1[7])));
        float b2 = __fadd_rn(__fadd_rn(__fadd_rn(s2[0], s2[1]), __fadd_rn(s2[2], s2[3])),
                             __fadd_rn(__fadd_rn(s2[4], s2[5]), __fadd_rn(s2[6], s2[7])));
        zzv[(pt << 6) + pl] = __fadd_rn(b1, b2);
    }

    // ---- 3-term MFMA: acc[rd][mf][nf], rd = code round (0..255 / 256..511)
    f32x4 acc[2][4][4];
    #pragma unroll
    for (int rd = 0; rd < 2; ++rd)
        #pragma unroll
        for (int mf = 0; mf < 4; ++mf)
            #pragma unroll
            for (int nf = 0; nf < 4; ++nf)
                acc[rd][mf][nf] = (f32x4){0.f, 0.f, 0.f, 0.f};

    for (int kk = 0; kk < 8; ++kk) {
        const int cc0 = kk * 32 + kg * 8;
        short8 ah[4], al[4];
        #pragma unroll
        for (int mf = 0; mf < 4; ++mf) {
            const float* zr = &zt[((mf << 4) + r16) * LDSW + cc0];
            #pragma unroll
            for (int j = 0; j < 8; ++j) {
                float zvf = zr[j];
                __hip_bfloat16 h = __float2bfloat16(zvf);
                float hf = __bfloat162float(h);
                __hip_bfloat16 l = __float2bfloat16(zvf - hf);   // exact residual
                ah[mf][j] = *reinterpret_cast<short*>(&h);
                al[mf][j] = *reinterpret_cast<short*>(&l);
            }
        }
        #pragma unroll
        for (int rd = 0; rd < 2; ++rd) {
            const int code0 = rd * 256 + w * 64;
            #pragma unroll
            for (int nf = 0; nf < 4; ++nf) {
                const int code = code0 + nf * 16 + r16;
                short8 bh = *reinterpret_cast<const short8*>(Ch + (size_t)code * C_DIM + cc0);
                short8 bl = *reinterpret_cast<const short8*>(Cl + (size_t)code * C_DIM + cc0);
                #pragma unroll
                for (int mf = 0; mf < 4; ++mf)
                    acc[rd][mf][nf] = __builtin_amdgcn_mfma_f32_16x16x32_bf16(ah[mf], bh, acc[rd][mf][nf], 0, 0, 0);
                #pragma unroll
                for (int mf = 0; mf < 4; ++mf)
                    acc[rd][mf][nf] = __builtin_amdgcn_mfma_f32_16x16x32_bf16(ah[mf], bl, acc[rd][mf][nf], 0, 0, 0);
                #pragma unroll
                for (int mf = 0; mf < 4; ++mf)
                    acc[rd][mf][nf] = __builtin_amdgcn_mfma_f32_16x16x32_bf16(al[mf], bh, acc[rd][mf][nf], 0, 0, 0);
            }
        }
    }

    // ---- per-lane top-2 over this lane's codes (ascending code order)
    float tb[16], ts[16];
    int   tc[16];
    #pragma unroll
    for (int s = 0; s < 16; ++s) { tb[s] = 3.4e38f; ts[s] = 3.4e38f; tc[s] = 0; }

    #pragma unroll
    for (int rd = 0; rd < 2; ++rd) {
        #pragma unroll
        for (int nf = 0; nf < 4; ++nf) {
            const int code = rd * 256 + w * 64 + nf * 16 + r16;
            const float cck = ccv[code];
            #pragma unroll
            for (int mf = 0; mf < 4; ++mf) {
                #pragma unroll
                for (int r = 0; r < 4; ++r) {
                    const int s = mf * 4 + r;
                    float d = __builtin_fmaf(-2.0f, acc[rd][mf][nf][r], cck);
                    if (d < tb[s]) { ts[s] = tb[s]; tb[s] = d; tc[s] = code; }
                    else if (d < ts[s]) { ts[s] = d; }
                }
            }
        }
    }

    // ---- cross-lane (r16) top-2 combine; lanes in a kg-group share pos set
    #pragma unroll
    for (int s = 0; s < 16; ++s) {
        #pragma unroll
        for (int m = 1; m <= 8; m <<= 1) {
            float ob = __shfl_xor(tb[s], m, 64);
            int   oc = __shfl_xor(tc[s], m, 64);
            float os = __shfl_xor(ts[s], m, 64);
            if (ob < tb[s] || (ob == tb[s] && oc < tc[s])) {
                ts[s] = fminf(tb[s], os); tb[s] = ob; tc[s] = oc;
            } else {
                ts[s] = fminf(ts[s], ob);
            }
        }
    }
    if (r16 == 0) {
        #pragma unroll
        for (int mf = 0; mf < 4; ++mf)
            #pragma unroll
            for (int r = 0; r < 4; ++r) {
                const int pl = mf * 16 + kg * 4 + r;
                wb[w][pl]   = tb[mf * 4 + r];
                wc[w][pl]   = tc[mf * 4 + r];
                wsec[w][pl] = ts[mf * 4 + r];
            }
    }
    __syncthreads();

    // ---- cross-wave combine (ascending wave = ascending code) + write
    if (w == 0) {
        float B = wb[0][lane]; int C = wc[0][lane]; float S = wsec[0][lane];
        #pragma unroll
        for (int ww = 1; ww < 4; ++ww) {
            float ob = wb[ww][lane]; int oc = wc[ww][lane]; float os = wsec[ww][lane];
            if (ob < B || (ob == B && oc < C)) { S = fminf(B, os); B = ob; C = oc; }
            else { S = fminf(S, ob); }
        }
        const int P = (pt << 6) + lane;
        bestd[P] = B; bestc[P] = C; secondd[P] = S;
    }
}

// ---------------------------------------------------------------------------
// Finalize-exact: per pos. Unambiguous -> one np-exact chain for best_c
// (proven numerics: ascending-c FMA via float4, d = fl(fl(zz-2dot)+cc)).
// Ambiguous -> push pos to amblist.
// ---------------------------------------------------------------------------
__global__ __launch_bounds__(256) void vq_finalize_kernel(
    const float* __restrict__ z, const float* __restrict__ cb,
    const float* __restrict__ ccv, const float* __restrict__ zzv,
    const float* __restrict__ bestd, const int* __restrict__ bestc,
    const float* __restrict__ secondd, int* __restrict__ amblist,
    int* __restrict__ ambcnt, int* __restrict__ idx, float* __restrict__ dmin)
{
    const int pos = blockIdx.x * 256 + threadIdx.x;
    if (secondd[pos] - bestd[pos] <= W_AMB) {
        int slot = atomicAdd(ambcnt, 1);
        amblist[slot] = pos;
        return;
    }
    const int code = bestc[pos];
    const float* zr = z + ((size_t)(pos >> 10) << 18) + (pos & 1023);
    const float4* crow4 = reinterpret_cast<const float4*>(cb + ((size_t)code << 8));
    float a0 = 0.f;
    for (int c4 = 0; c4 < 64; ++c4) {
        float4 cv = crow4[c4];
        a0 = __builtin_fmaf(zr[(size_t)(c4 * 4 + 0) << 10], cv.x, a0);
        a0 = __builtin_fmaf(zr[(size_t)(c4 * 4 + 1) << 10], cv.y, a0);
        a0 = __builtin_fmaf(zr[(size_t)(c4 * 4 + 2) << 10], cv.z, a0);
        a0 = __builtin_fmaf(zr[(size_t)(c4 * 4 + 3) << 10], cv.w, a0);
    }
    float d = __fadd_rn(__fsub_rn(zzv[pos], __fmul_rn(2.0f, a0)), ccv[code]);
    idx[pos]  = code;
    dmin[pos] = d;
}

// ---------------------------------------------------------------------------
// Ambiguous positions: full 512-code np-exact argmin, one pos per block-turn.
// 2 chains/thread, z row broadcast from LDS, deterministic first-min reduce.
// ---------------------------------------------------------------------------
__global__ __launch_bounds__(256) void vq_amb_kernel(
    const float* __restrict__ z, const float* __restrict__ cb,
    const float* __restrict__ ccv, const float* __restrict__ zzv,
    const int* __restrict__ amblist, const int* __restrict__ ambcnt,
    int* __restrict__ idx, float* __restrict__ dmin)
{
    const int tid = threadIdx.x;
    const int count = *ambcnt;
    __shared__ float zrow[256];
    __shared__ float sd[256];
    __shared__ int   sc[256];

    for (int e = blockIdx.x; e < count; e += 256) {
        const int pos = amblist[e];
        const float* zr = z + ((size_t)(pos >> 10) << 18) + (pos & 1023);
        zrow[tid] = zr[(size_t)tid << 10];
        __syncthreads();

        const float zzp = zzv[pos];
        float bd = 3.4e38f; int bc = 0;
        #pragma unroll
        for (int h = 0; h < 2; ++h) {
            const int code = h * 256 + tid;
            const float4* crow4 = reinterpret_cast<const float4*>(cb + ((size_t)code << 8));
            float a0 = 0.f;
            for (int c4 = 0; c4 < 64; ++c4) {
                float4 cv = crow4[c4];
                a0 = __builtin_fmaf(zrow[c4 * 4 + 0], cv.x, a0);
                a0 = __builtin_fmaf(zrow[c4 * 4 + 1], cv.y, a0);
                a0 = __builtin_fmaf(zrow[c4 * 4 + 2], cv.z, a0);
                a0 = __builtin_fmaf(zrow[c4 * 4 + 3], cv.w, a0);
            }
            float d = __fadd_rn(__fsub_rn(zzp, __fmul_rn(2.0f, a0)), ccv[code]);
            if (d < bd) { bd = d; bc = code; }     // h ascending -> code ascending
        }
        sd[tid] = bd; sc[tid] = bc;
        __syncthreads();
        for (int off = 128; off > 0; off >>= 1) {
            if (tid < off) {
                float od = sd[tid + off]; int oc = sc[tid + off];
                if (od < sd[tid] || (od == sd[tid] && oc < sc[tid])) { sd[tid] = od; sc[tid] = oc; }
            }
            __syncthreads();
        }
        if (tid == 0) { idx[pos] = sc[0]; dmin[pos] = sd[0]; }
        __syncthreads();
    }
}

// ---------------------------------------------------------------------------
// out1 = float(idx); block-sum dmin -> partials[256]
// ---------------------------------------------------------------------------
__global__ __launch_bounds__(256) void vq_out1_reduce_kernel(
    const int* __restrict__ idx, const float* __restrict__ dmin,
    float* __restrict__ out1, float* __restrict__ partials)
{
    const int t = threadIdx.x;
    const int pos = blockIdx.x * 256 + t;
    out1[pos] = (float)idx[pos];
    __shared__ float s[256];
    s[t] = dmin[pos];
    __syncthreads();
    for (int off = 128; off > 0; off >>= 1) {
        if (t < off) s[t] += s[t + off];
        __syncthreads();
    }
    if (t == 0) partials[blockIdx.x] = s[0];
}

// ---------------------------------------------------------------------------
// Gather: out0[b, c, hw] = cb[code][c]  (proven)
// ---------------------------------------------------------------------------
__global__ __launch_bounds__(256) void vq_gather_kernel(
    const float* __restrict__ cb, const int* __restrict__ idx,
    float* __restrict__ out0)
{
    const int blk = blockIdx.x;
    const int b   = blk >> 4;
    const int hw0 = (blk & 15) << 6;
    const int lane = threadIdx.x & 63;
    const int w    = threadIdx.x >> 6;

    __shared__ int sidx[64];
    if (threadIdx.x < 64) sidx[threadIdx.x] = idx[(blk << 6) + threadIdx.x];
    __syncthreads();

    const int code = sidx[lane];
    const float4* crow4 = reinterpret_cast<const float4*>(cb + ((size_t)code << 8) + (w << 6));
    float* ob = out0 + ((size_t)b << 18) + ((size_t)(w * 64) << 10) + hw0 + lane;
    #pragma unroll 4
    for (int j4 = 0; j4 < 16; ++j4) {
        float4 v = crow4[j4];
        ob[(size_t)(j4 * 4 + 0) << 10] = v.x;
        ob[(size_t)(j4 * 4 + 1) << 10] = v.y;
        ob[(size_t)(j4 * 4 + 2) << 10] = v.z;
        ob[(size_t)(j4 * 4 + 3) << 10] = v.w;
    }
}

// ---------------------------------------------------------------------------
// loss = 1.25 * sum(partials) / 2^24
// ---------------------------------------------------------------------------
__global__ __launch_bounds__(256) void vq_loss_kernel(
    const float* __restrict__ partials, float* __restrict__ out2)
{
    __shared__ float s[256];
    const int t = threadIdx.x;
    s[t] = partials[t];
    __syncthreads();
    for (int off = 128; off > 0; off >>= 1) {
        if (t < off) s[t] += s[t + off];
        __syncthreads();
    }
    if (t == 0)
        out2[0] = 1.25f * (s[0] * (1.0f / 16777216.0f));
}

// ---------------------------------------------------------------------------
extern "C" void kernel_launch(void* const* d_in, const int* in_sizes, int n_in,
                              void* d_out, int out_size, void* d_ws, size_t ws_size,
                              hipStream_t stream)
{
    const float* z  = (const float*)d_in[0];
    const float* cb = (const float*)d_in[1];

    float* out0 = (float*)d_out;
    float* out1 = out0 + OUT0_ELEMS;
    float* out2 = out1 + OUT1_ELEMS;

    // scratch in out0 (dead before gather):
    float* zzv     = out0;                 // 65536
    float* bestd   = out0 + 65536;         // 65536
    float* secondd = out0 + 131072;        // 65536
    float* dmin    = out0 + 196608;        // 65536
    int*   bestc   = (int*)(out0 + 262144);  // 65536
    int*   amblist = (int*)(out0 + 327680);  // 65536

    // ws (~790 KB, proven envelope):
    float* wsf      = (float*)d_ws;
    float* ccv      = wsf;                                   // 512
    float* partials = wsf + 512;                             // 256
    int*   ambcnt   = (int*)(wsf + 768);                     // 1 (pad to 1024)
    __hip_bfloat16* Ch = (__hip_bfloat16*)(wsf + 1024);      // 131072 bf16
    __hip_bfloat16* Cl = (__hip_bfloat16*)(wsf + 66560);     // 131072 bf16
    int* idx        = (int*)(wsf + 132096);                  // 65536 i32

    hipMemsetAsync(ambcnt, 0, sizeof(int), stream);
    hipLaunchKernelGGL(vq_convcb_kernel,   dim3(512),  dim3(256), 0, stream, cb, Ch, Cl);
    hipLaunchKernelGGL(vq_cc_kernel,       dim3(2),    dim3(256), 0, stream, cb, ccv);
    hipLaunchKernelGGL(vq_screen_kernel,   dim3(1024), dim3(256), 0, stream,
                       z, Ch, Cl, ccv, zzv, bestd, bestc, secondd);
    hipLaunchKernelGGL(vq_finalize_kernel, dim3(256),  dim3(256), 0, stream,
                       z, cb, ccv, zzv, bestd, bestc, secondd, amblist, ambcnt, idx, dmin);
    hipLaunchKernelGGL(vq_amb_kernel,      dim3(256),  dim3(256), 0, stream,
                       z, cb, ccv, zzv, amblist, ambcnt, idx, dmin);
    hipLaunchKernelGGL(vq_out1_reduce_kernel, dim3(256), dim3(256), 0, stream,
                       idx, dmin, out1, partials);
    hipLaunchKernelGGL(vq_gather_kernel,   dim3(1024), dim3(256), 0, stream, cb, idx, out0);
    hipLaunchKernelGGL(vq_loss_kernel,     dim3(1),    dim3(256), 0, stream, partials, out2);
}